// Round 7
// baseline (656.236 us; speedup 1.0000x reference)
//
#include <hip/hip_runtime.h>
#include <math.h>

#define NROWS 16384
#define DIM   512
#define NPROTO 4096
#define TINV (1.0f / 0.9f)
#define LOSS_OFF ((size_t)NROWS * DIM)
#define IDX_OFF  ((size_t)NROWS * DIM + 1)

typedef __attribute__((ext_vector_type(8))) short short8;
typedef __attribute__((ext_vector_type(4))) float f32x4;

__global__ void zero_loss_kernel(float* out) { out[LOSS_OFF] = 0.0f; }

static __device__ __forceinline__ unsigned short f2bf(float x) {
    unsigned u = __float_as_uint(x);
    u = (u + 0x7fffu + ((u >> 16) & 1u)) >> 16;
    return (unsigned short)u;
}
static __device__ __forceinline__ float bf2f(unsigned short b) {
    return __uint_as_float(((unsigned)b) << 16);
}
static __device__ __forceinline__ void gl_lds16(const void* g, void* l) {
    __builtin_amdgcn_global_load_lds((const __attribute__((address_space(1))) unsigned int*)g,
                                     (__attribute__((address_space(3))) unsigned int*)l, 16, 0, 0);
}

// ---------------- pre-split: fp32 -> (hi, mid) bf16 in k-group-major tiled layout ----------------
// dst layout: [cgroup 0..63][row 0..nrows-1][8 bf16], cgroup c covers k = c*8 .. c*8+8
__global__ __launch_bounds__(256)
void split_bf16_kernel(const float* __restrict__ src, unsigned short* __restrict__ dhi,
                       unsigned short* __restrict__ dmid, int nrows)
{
    __shared__ __align__(16) unsigned short shi[64][520];
    __shared__ __align__(16) unsigned short smid[64][520];
    const int tid = threadIdx.x;
    const int r0 = blockIdx.x * 64;
#pragma unroll
    for (int q = 0; q < 32; ++q) {
        int idx = q * 256 + tid;
        int row = idx >> 7;
        int k4 = (idx & 127) << 2;
        float4 v = *(const float4*)&src[(size_t)(r0 + row) * DIM + k4];
        unsigned short h0 = f2bf(v.x), h1 = f2bf(v.y), h2 = f2bf(v.z), h3 = f2bf(v.w);
        shi[row][k4] = h0; shi[row][k4 + 1] = h1; shi[row][k4 + 2] = h2; shi[row][k4 + 3] = h3;
        smid[row][k4]     = f2bf(v.x - bf2f(h0));
        smid[row][k4 + 1] = f2bf(v.y - bf2f(h1));
        smid[row][k4 + 2] = f2bf(v.z - bf2f(h2));
        smid[row][k4 + 3] = f2bf(v.w - bf2f(h3));
    }
    __syncthreads();
    const int row = tid & 63;
#pragma unroll
    for (int i = 0; i < 16; ++i) {
        int c = i * 4 + (tid >> 6);
        size_t o = (size_t)c * nrows + r0 + row;
        ((ulonglong2*)dhi)[o]  = *(const ulonglong2*)&shi[row][c * 8];
        ((ulonglong2*)dmid)[o] = *(const ulonglong2*)&smid[row][c * 8];
    }
}

// ---------------- fused MFMA kernel: 8 waves, BM=32, BN=256, BK=32, A resident in LDS ----------------
#define BM 32
#define BN 256
#define NCHUNK (NPROTO / BN)        // 16
#define NT (DIM / 32)               // 16 t-steps per chunk
#define NW 8
#define CAP 64
#define PRUNE_AT 48
#define THRH 12.0f

__global__ __launch_bounds__(512, 2)
void attr_proto_mfma(const float* __restrict__ A, const float* __restrict__ Pr,
                     const float* __restrict__ U, float* __restrict__ out,
                     const unsigned short* __restrict__ wsAhi, const unsigned short* __restrict__ wsAmid,
                     const unsigned short* __restrict__ wsPhi, const unsigned short* __restrict__ wsPmid)
{
    __shared__ __align__(16) unsigned short sAr[2][NT][4][BM][8];   // A resident: [sp][tt][g][row][8]  64 KB
    __shared__ __align__(16) unsigned short sPd[2][2][4][BN][8];    // P dbuf: [buf][sp][g][proto][8]   64 KB
    __shared__ float hZ[BM][CAP];                                   // 8 KB
    __shared__ unsigned short hI[BM][CAP];                          // 4 KB
    __shared__ int cnt[BM];
    __shared__ float mRun[BM], lRun[BM];
    __shared__ float wMax[NW][BM], wSum[NW][BM];
    __shared__ float epZ[16][BM];
    __shared__ int epI[16][BM];
    __shared__ int pruneFlag;

    const int tid = threadIdx.x;
    const int w = tid >> 6;          // 0..7
    const int lane = tid & 63;
    const int l4 = lane & 15;
    const int lh = lane >> 4;
    const int row0 = blockIdx.x * BM;

    for (int r = tid; r < BM; r += 512) { cnt[r] = 0; mRun[r] = -1e30f; lRun[r] = 0.f; }
    if (tid == 0) pruneFlag = 0;

    // ---- stage P tile (t, pbase) into buffer b: 32 wave-instrs, 4 per wave
    auto STAGE_P = [&](int b, int t, int pbase) {
#pragma unroll
        for (int q = 0; q < 4; ++q) {
            int i = w * 4 + q;               // 0..31
            int sp = i >> 4, g = (i >> 2) & 3, qrt = i & 3;
            const unsigned short* base = sp ? wsPmid : wsPhi;
            gl_lds16(base + ((size_t)(t * 4 + g) * NPROTO + pbase + qrt * 64 + lane) * 8,
                     &sPd[b][sp][g][qrt * 64][0]);
        }
    };

    // ---- prologue: stage resident A (64 wave-instrs, 8 per wave) + first P tile
#pragma unroll
    for (int q = 0; q < 8; ++q) {
        int i = w * 8 + q;                   // 0..63
        int sp = i >> 5, tt = (i >> 1) & 15, gpair = i & 1;
        const unsigned short* base = sp ? wsAmid : wsAhi;
        gl_lds16(base + ((size_t)(tt * 4 + gpair * 2 + (lane >> 5)) * NROWS + row0 + (lane & 31)) * 8,
                 &sAr[sp][tt][gpair * 2][0][0]);
    }
    STAGE_P(0, 0, 0);
    __syncthreads();   // compiler drains vmcnt(0): A + P tile0 ready; also covers init stores

    for (int ch = 0; ch < NCHUNK; ++ch) {
        const int pbase = ch * BN;
        f32x4 acc[2][2];
#pragma unroll
        for (int mf = 0; mf < 2; ++mf)
#pragma unroll
            for (int nf = 0; nf < 2; ++nf) { acc[mf][nf][0]=0.f; acc[mf][nf][1]=0.f; acc[mf][nf][2]=0.f; acc[mf][nf][3]=0.f; }

#pragma unroll 2
        for (int t = 0; t < NT; ++t) {
            const int cur = t & 1;
            // issue next P tile's loads first (L2-hot; overlap with compute below)
            if (t < NT - 1)            STAGE_P(cur ^ 1, t + 1, pbase);
            else if (ch + 1 < NCHUNK)  STAGE_P(cur ^ 1, 0, pbase + BN);
            // compute current tile: K=32 (g = lh), A from resident LDS
            short8 a[2][2], b[2][2];
#pragma unroll
            for (int mf = 0; mf < 2; ++mf) {
                a[mf][0] = *(const short8*)&sAr[0][t][lh][mf * 16 + l4][0];
                a[mf][1] = *(const short8*)&sAr[1][t][lh][mf * 16 + l4][0];
            }
#pragma unroll
            for (int nf = 0; nf < 2; ++nf) {
                b[nf][0] = *(const short8*)&sPd[cur][0][lh][w * 32 + nf * 16 + l4][0];
                b[nf][1] = *(const short8*)&sPd[cur][1][lh][w * 32 + nf * 16 + l4][0];
            }
#pragma unroll
            for (int mf = 0; mf < 2; ++mf)
#pragma unroll
                for (int nf = 0; nf < 2; ++nf) {
                    acc[mf][nf] = __builtin_amdgcn_mfma_f32_16x16x32_bf16(a[mf][0], b[nf][0], acc[mf][nf], 0, 0, 0);
                    acc[mf][nf] = __builtin_amdgcn_mfma_f32_16x16x32_bf16(a[mf][0], b[nf][1], acc[mf][nf], 0, 0, 0);
                    acc[mf][nf] = __builtin_amdgcn_mfma_f32_16x16x32_bf16(a[mf][1], b[nf][0], acc[mf][nf], 0, 0, 0);
                }
            __syncthreads();   // next buf written (per-wave vmcnt drain); all waves done reading cur
        }

        // ---- gumbel: acc -> z in place.  D layout: row=(lane>>4)*4+reg, col=lane&15
#pragma unroll
        for (int mf = 0; mf < 2; ++mf) {
            float uu[8];
            const int rb = row0 + mf * 16 + lh * 4;
#pragma unroll
            for (int nf = 0; nf < 2; ++nf)
#pragma unroll
                for (int r = 0; r < 4; ++r)
                    uu[nf * 4 + r] = U[(size_t)(rb + r) * NPROTO + pbase + w * 32 + nf * 16 + l4];
#pragma unroll
            for (int nf = 0; nf < 2; ++nf)
#pragma unroll
                for (int r = 0; r < 4; ++r) {
                    float g = -__logf(-__logf(uu[nf * 4 + r] + 1e-10f) + 1e-10f);
                    acc[mf][nf][r] = (acc[mf][nf][r] + g) * TINV;
                }
        }
        // wave-slice row max
#pragma unroll
        for (int mf = 0; mf < 2; ++mf) {
            f32x4 rm;
#pragma unroll
            for (int r = 0; r < 4; ++r)
                rm[r] = fmaxf(acc[mf][0][r], acc[mf][1][r]);
#pragma unroll
            for (int off = 1; off < 16; off <<= 1)
#pragma unroll
                for (int r = 0; r < 4; ++r) rm[r] = fmaxf(rm[r], __shfl_xor(rm[r], off));
            if (l4 == 0)
#pragma unroll
                for (int r = 0; r < 4; ++r) wMax[w][mf * 16 + lh * 4 + r] = rm[r];
        }
        __syncthreads();
        // sums + heavy-list inserts
#pragma unroll
        for (int mf = 0; mf < 2; ++mf) {
#pragma unroll
            for (int r = 0; r < 4; ++r) {
                const int rl = mf * 16 + lh * 4 + r;
                float gm = wMax[0][rl];
#pragma unroll
                for (int q = 1; q < NW; ++q) gm = fmaxf(gm, wMax[q][rl]);
                float mn = fmaxf(mRun[rl], gm);
                float s = 0.f;
#pragma unroll
                for (int nf = 0; nf < 2; ++nf) s += __expf(acc[mf][nf][r] - mn);
#pragma unroll
                for (int off = 1; off < 16; off <<= 1) s += __shfl_xor(s, off);
                if (l4 == 0) wSum[w][rl] = s;
                float thrv = mn - THRH;
#pragma unroll
                for (int nf = 0; nf < 2; ++nf) {
                    float z = acc[mf][nf][r];
                    if (z > thrv) {
                        int pos = atomicAdd(&cnt[rl], 1);
                        if (pos < CAP) { hZ[rl][pos] = z; hI[rl][pos] = (unsigned short)(pbase + w * 32 + nf * 16 + l4); }
                    }
                }
            }
        }
        __syncthreads();
        if (tid < BM) {
            float gm = wMax[0][tid];
#pragma unroll
            for (int q = 1; q < NW; ++q) gm = fmaxf(gm, wMax[q][tid]);
            float mn = fmaxf(mRun[tid], gm);
            float S = 0.f;
#pragma unroll
            for (int q = 0; q < NW; ++q) S += wSum[q][tid];
            lRun[tid] = lRun[tid] * __expf(mRun[tid] - mn) + S;
            mRun[tid] = mn;
            if (cnt[tid] > PRUNE_AT) atomicOr(&pruneFlag, 1);
        }
        __syncthreads();
        if (pruneFlag) {
            for (int r = 0; r < BM; ++r) {
                int c0 = min(cnt[r], CAP);
                if (c0 > PRUNE_AT) {
                    float thr2 = mRun[r] - THRH;
                    float ez = 0.f; int ei = 0; bool keep = false;
                    if (tid < c0) { ez = hZ[r][tid]; ei = hI[r][tid]; keep = ez > thr2; }
                    __syncthreads();
                    if (tid == 0) cnt[r] = 0;
                    __syncthreads();
                    if (keep) { int pos = atomicAdd(&cnt[r], 1); hZ[r][pos] = ez; hI[r][pos] = (unsigned short)ei; }
                    __syncthreads();
                }
            }
            if (tid == 0) pruneFlag = 0;
        }
        __syncthreads();
    }

    // ---------------- epilogue phase 1: argmax via r1-replica fp32 serial recompute ----------------
    // np reference computes dist in fp32; serial fp32 FMA z matches it on this dataset (r1/r4/r5/r6 PASS).
    __syncthreads();
    const int rq = tid & 31;     // row within block
    const int qq = tid >> 5;     // 16 groups per row
    {
        const int c = min(cnt[rq], CAP);
        float qm = -1e30f;
        for (int e = qq; e < c; e += 16) qm = fmaxf(qm, hZ[rq][e]);
        epZ[qq][rq] = qm;
    }
    __syncthreads();
    {
        const int c = min(cnt[rq], CAP);
        float bzr = epZ[0][rq];
#pragma unroll
        for (int q = 1; q < 16; ++q) bzr = fmaxf(bzr, epZ[q][rq]);
        const float win = bzr - 3.0f;
        float bestz = -1e30f; int bestp = 1 << 30;
        const float* ap = &A[(size_t)(row0 + rq) * DIM];
        for (int e = qq; e < c; e += 16) {
            if (hZ[rq][e] > win) {
                const int p = hI[rq][e];
                const float* pp = &Pr[(size_t)p * DIM];
                float d = 0.f;
                for (int k = 0; k < DIM; k += 4) {       // serial k order == r1's accumulation
                    float4 av = *(const float4*)&ap[k];
                    float4 pv = *(const float4*)&pp[k];
                    d = fmaf(av.x, pv.x, d);
                    d = fmaf(av.y, pv.y, d);
                    d = fmaf(av.z, pv.z, d);
                    d = fmaf(av.w, pv.w, d);
                }
                float u = U[(size_t)(row0 + rq) * NPROTO + p];
                float g = -logf(-logf(u + 1e-10f) + 1e-10f);  // accurate logf, as r1
                float zz = (d + g) * (1.0f / 0.9f);
                if (zz > bestz || (zz == bestz && p < bestp)) { bestz = zz; bestp = p; }
            }
        }
        __syncthreads();
        epZ[qq][rq] = bestz;
        epI[qq][rq] = bestp;
    }
    __syncthreads();
    if (tid < BM) {
        float bz2 = epZ[0][tid]; int bp2 = epI[0][tid];
#pragma unroll
        for (int q = 1; q < 16; ++q) {
            float z = epZ[q][tid]; int p = epI[q][tid];
            if (z > bz2 || (z == bz2 && p < bp2)) { bz2 = z; bp2 = p; }
        }
        out[IDX_OFF + row0 + tid] = (float)bp2;
    }

    // ---------------- epilogue phase 2: sparse PV gather, output write, loss ----------------
    float lossAcc = 0.f;
    for (int r = w; r < BM; r += NW) {
        const int grow = row0 + r;
        const int c = min(cnt[r], CAP);
        const float mm = mRun[r];
        const float li = 1.0f / lRun[r];
        float o[8];
#pragma unroll
        for (int q = 0; q < 8; ++q) o[q] = 0.f;
        for (int e = 0; e < c; ++e) {
            float wgt = __expf(hZ[r][e] - mm) * li;
            const float* pp = &Pr[(size_t)hI[r][e] * DIM + lane * 8];
            float4 p0 = *(const float4*)pp;
            float4 p1 = *(const float4*)(pp + 4);
            o[0] += wgt * p0.x; o[1] += wgt * p0.y; o[2] += wgt * p0.z; o[3] += wgt * p0.w;
            o[4] += wgt * p1.x; o[5] += wgt * p1.y; o[6] += wgt * p1.z; o[7] += wgt * p1.w;
        }
        const float* fr = &A[(size_t)grow * DIM + lane * 8];
        float4 f0 = *(const float4*)fr; float4 f1 = *(const float4*)(fr + 4);
        *(float4*)&out[(size_t)grow * DIM + lane * 8]     = make_float4(o[0], o[1], o[2], o[3]);
        *(float4*)&out[(size_t)grow * DIM + lane * 8 + 4] = make_float4(o[4], o[5], o[6], o[7]);
        lossAcc += fabsf(o[0] - f0.x) + fabsf(o[1] - f0.y) + fabsf(o[2] - f0.z) + fabsf(o[3] - f0.w)
                 + fabsf(o[4] - f1.x) + fabsf(o[5] - f1.y) + fabsf(o[6] - f1.z) + fabsf(o[7] - f1.w);
    }
#pragma unroll
    for (int off = 1; off < 64; off <<= 1) lossAcc += __shfl_xor(lossAcc, off);
    if (lane == 0) atomicAdd(&out[LOSS_OFF], lossAcc * (1.0f / ((float)NROWS * (float)DIM)));
}

// ---------------- fallback: r1 fp32 VALU kernel (used if ws too small) ----------------
#define FCAP 192
#define FTHR 20.0f

__global__ __launch_bounds__(256, 1)
void attr_proto_fused_valu(const float* __restrict__ A, const float* __restrict__ Pr,
                           const float* __restrict__ U, float* __restrict__ out)
{
    __shared__ __align__(16) float As[64][64 + 4];
    __shared__ __align__(16) float Bs[128][64 + 4];
    __shared__ float hZ[64][FCAP];
    __shared__ unsigned short hI[64][FCAP];
    __shared__ int cnt[64];
    __shared__ float mArr[64];
    __shared__ float lArr[64];
    __shared__ int pruneFlag;

    const int tid = threadIdx.x;
    const int tx = tid & 31;
    const int ty = tid >> 5;
    const int row0 = blockIdx.x * 64;

    for (int r = tid; r < 64; r += 256) cnt[r] = 0;
    if (tid == 0) pruneFlag = 0;

    float m[8], l[8], bz[8];
    int bi[8];
#pragma unroll
    for (int i = 0; i < 8; ++i) { m[i] = -INFINITY; l[i] = 0.0f; bz[i] = -INFINITY; bi[i] = 0; }
    __syncthreads();

    for (int ch = 0; ch < 32; ++ch) {
        const int pbase = ch * 128;
        float acc[8][4];
#pragma unroll
        for (int i = 0; i < 8; ++i)
#pragma unroll
            for (int j = 0; j < 4; ++j) acc[i][j] = 0.0f;

        for (int kk = 0; kk < DIM; kk += 64) {
#pragma unroll
            for (int q = 0; q < 4; ++q) {
                int lin = tid + q * 256;
                int lr = lin >> 4; int kq = (lin & 15) << 2;
                *(float4*)&As[lr][kq] = *(const float4*)&A[(size_t)(row0 + lr) * DIM + kk + kq];
            }
#pragma unroll
            for (int q = 0; q < 8; ++q) {
                int lin = tid + q * 256;
                int pr = lin >> 4; int kq = (lin & 15) << 2;
                *(float4*)&Bs[pr][kq] = *(const float4*)&Pr[(size_t)(pbase + pr) * DIM + kk + kq];
            }
            __syncthreads();
#pragma unroll 4
            for (int k4 = 0; k4 < 64; k4 += 4) {
                float4 av[8], bv[4];
#pragma unroll
                for (int i = 0; i < 8; ++i) av[i] = *(const float4*)&As[ty * 8 + i][k4];
#pragma unroll
                for (int j = 0; j < 4; ++j) bv[j] = *(const float4*)&Bs[tx + 32 * j][k4];
#pragma unroll
                for (int i = 0; i < 8; ++i)
#pragma unroll
                    for (int j = 0; j < 4; ++j) {
                        acc[i][j] += av[i].x * bv[j].x; acc[i][j] += av[i].y * bv[j].y;
                        acc[i][j] += av[i].z * bv[j].z; acc[i][j] += av[i].w * bv[j].w;
                    }
            }
            __syncthreads();
        }
#pragma unroll
        for (int i = 0; i < 8; ++i) {
            const int ri = ty * 8 + i;
            const size_t urow = (size_t)(row0 + ri) * NPROTO + pbase;
            float z[4]; float lmax = -INFINITY;
#pragma unroll
            for (int j = 0; j < 4; ++j) {
                float u = U[urow + tx + 32 * j];
                float g = -logf(-logf(u + 1e-10f) + 1e-10f);
                z[j] = (acc[i][j] + g) * TINV;
                lmax = fmaxf(lmax, z[j]);
            }
#pragma unroll
            for (int off = 16; off; off >>= 1) lmax = fmaxf(lmax, __shfl_xor(lmax, off, 32));
            const float mn = fmaxf(m[i], lmax);
            float s = 0.0f;
#pragma unroll
            for (int j = 0; j < 4; ++j) s += expf(z[j] - mn);
#pragma unroll
            for (int off = 16; off; off >>= 1) s += __shfl_xor(s, off, 32);
            l[i] = l[i] * expf(m[i] - mn) + s;
            m[i] = mn;
#pragma unroll
            for (int j = 0; j < 4; ++j) {
                const int p = pbase + tx + 32 * j;
                if (z[j] > bz[i]) { bz[i] = z[j]; bi[i] = p; }
                if (z[j] > mn - FTHR) {
                    int pos = atomicAdd(&cnt[ri], 1);
                    if (pos < FCAP) { hZ[ri][pos] = z[j]; hI[ri][pos] = (unsigned short)p; }
                }
            }
            if (tx == 0) {
                mArr[ri] = mn;
                if (cnt[ri] > 64) atomicOr(&pruneFlag, 1);
            }
        }
        __syncthreads();
        if (pruneFlag) {
            for (int r = 0; r < 64; ++r) {
                const int c0 = min(cnt[r], FCAP);
                if (c0 > 64) {
                    const float thr = mArr[r] - FTHR;
                    float ez = 0.0f; int ei = 0; bool keep = false;
                    if (tid < c0) { ez = hZ[r][tid]; ei = hI[r][tid]; keep = (ez > thr); }
                    __syncthreads();
                    if (tid == 0) cnt[r] = 0;
                    __syncthreads();
                    if (keep) { int pos = atomicAdd(&cnt[r], 1); hZ[r][pos] = ez; hI[r][pos] = (unsigned short)ei; }
                    __syncthreads();
                }
            }
            if (tid == 0) pruneFlag = 0;
            __syncthreads();
        }
    }
#pragma unroll
    for (int i = 0; i < 8; ++i) {
        const int ri = ty * 8 + i;
        float vz = bz[i]; int vi = bi[i];
#pragma unroll
        for (int off = 16; off; off >>= 1) {
            float oz = __shfl_xor(vz, off, 32); int oi = __shfl_xor(vi, off, 32);
            if (oz > vz || (oz == vz && oi < vi)) { vz = oz; vi = oi; }
        }
        if (tx == 0) { lArr[ri] = l[i]; out[IDX_OFF + row0 + ri] = (float)vi; }
    }
    __syncthreads();

    const int wv = tid >> 6;
    const int lane = tid & 63;
    float lossAcc = 0.0f;
    for (int r = wv; r < 64; r += 4) {
        const int grow = row0 + r;
        const int c = min(cnt[r], FCAP);
        const float mm = mArr[r];
        const float li = 1.0f / lArr[r];
        float o[8];
#pragma unroll
        for (int q = 0; q < 8; ++q) o[q] = 0.0f;
        for (int e = 0; e < c; ++e) {
            const float wg = expf(hZ[r][e] - mm) * li;
            const float* pp = &Pr[(size_t)hI[r][e] * DIM + lane * 8];
            float4 p0 = *(const float4*)pp; float4 p1 = *(const float4*)(pp + 4);
            o[0] += wg * p0.x; o[1] += wg * p0.y; o[2] += wg * p0.z; o[3] += wg * p0.w;
            o[4] += wg * p1.x; o[5] += wg * p1.y; o[6] += wg * p1.z; o[7] += wg * p1.w;
        }
        const float* fr = &A[(size_t)grow * DIM + lane * 8];
        float4 f0 = *(const float4*)fr; float4 f1 = *(const float4*)(fr + 4);
        *(float4*)&out[(size_t)grow * DIM + lane * 8]     = make_float4(o[0], o[1], o[2], o[3]);
        *(float4*)&out[(size_t)grow * DIM + lane * 8 + 4] = make_float4(o[4], o[5], o[6], o[7]);
        lossAcc += fabsf(o[0]-f0.x) + fabsf(o[1]-f0.y) + fabsf(o[2]-f0.z) + fabsf(o[3]-f0.w)
                 + fabsf(o[4]-f1.x) + fabsf(o[5]-f1.y) + fabsf(o[6]-f1.z) + fabsf(o[7]-f1.w);
    }
#pragma unroll
    for (int off = 32; off; off >>= 1) lossAcc += __shfl_xor(lossAcc, off, 64);
    if (lane == 0) atomicAdd(&out[LOSS_OFF], lossAcc * (1.0f / ((float)NROWS * (float)DIM)));
}

extern "C" void kernel_launch(void* const* d_in, const int* in_sizes, int n_in,
                              void* d_out, int out_size, void* d_ws, size_t ws_size,
                              hipStream_t stream)
{
    const float* A  = (const float*)d_in[0];
    const float* Pr = (const float*)d_in[1];
    const float* U  = (const float*)d_in[2];
    float* out = (float*)d_out;

    const size_t NA = (size_t)NROWS * DIM;     // 8388608 shorts per A split
    const size_t NP = (size_t)NPROTO * DIM;    // 2097152 shorts per P split
    const size_t need = (2 * NA + 2 * NP) * sizeof(unsigned short);   // 41,943,040 B

    if (ws_size >= need) {
        unsigned short* wsAhi  = (unsigned short*)d_ws;
        unsigned short* wsAmid = wsAhi + NA;
        unsigned short* wsPhi  = wsAmid + NA;
        unsigned short* wsPmid = wsPhi + NP;
        split_bf16_kernel<<<NROWS / 64, 256, 0, stream>>>(A, wsAhi, wsAmid, NROWS);
        split_bf16_kernel<<<NPROTO / 64, 256, 0, stream>>>(Pr, wsPhi, wsPmid, NPROTO);
        zero_loss_kernel<<<1, 1, 0, stream>>>(out);
        attr_proto_mfma<<<NROWS / BM, 512, 0, stream>>>(A, Pr, U, out, wsAhi, wsAmid, wsPhi, wsPmid);
    } else {
        zero_loss_kernel<<<1, 1, 0, stream>>>(out);
        attr_proto_fused_valu<<<NROWS / 64, 256, 0, stream>>>(A, Pr, U, out);
    }
}

// Round 8
// 477.960 us; speedup vs baseline: 1.3730x; 1.3730x over previous
//
#include <hip/hip_runtime.h>
#include <math.h>

#define NROWS 16384
#define DIM   512
#define NPROTO 4096
#define TINV (1.0f / 0.9f)
#define LOSS_OFF ((size_t)NROWS * DIM)
#define IDX_OFF  ((size_t)NROWS * DIM + 1)

typedef __attribute__((ext_vector_type(8))) short short8;
typedef __attribute__((ext_vector_type(4))) float f32x4;

__global__ void zero_loss_kernel(float* out) { out[LOSS_OFF] = 0.0f; }

static __device__ __forceinline__ unsigned short f2bf(float x) {
    unsigned u = __float_as_uint(x);
    u = (u + 0x7fffu + ((u >> 16) & 1u)) >> 16;
    return (unsigned short)u;
}
static __device__ __forceinline__ float bf2f(unsigned short b) {
    return __uint_as_float(((unsigned)b) << 16);
}
static __device__ __forceinline__ void gl_lds16(const void* g, void* l) {
    __builtin_amdgcn_global_load_lds((const __attribute__((address_space(1))) unsigned int*)g,
                                     (__attribute__((address_space(3))) unsigned int*)l, 16, 0, 0);
}

// ---------------- pre-split: fp32 -> (hi, mid) bf16 in k-group-major tiled layout ----------------
// dst layout: [cgroup 0..63][row 0..nrows-1][8 bf16], cgroup c covers k = c*8 .. c*8+8
__global__ __launch_bounds__(256)
void split_bf16_kernel(const float* __restrict__ src, unsigned short* __restrict__ dhi,
                       unsigned short* __restrict__ dmid, int nrows)
{
    __shared__ __align__(16) unsigned short shi[64][520];
    __shared__ __align__(16) unsigned short smid[64][520];
    const int tid = threadIdx.x;
    const int r0 = blockIdx.x * 64;
#pragma unroll
    for (int q = 0; q < 32; ++q) {
        int idx = q * 256 + tid;
        int row = idx >> 7;
        int k4 = (idx & 127) << 2;
        float4 v = *(const float4*)&src[(size_t)(r0 + row) * DIM + k4];
        unsigned short h0 = f2bf(v.x), h1 = f2bf(v.y), h2 = f2bf(v.z), h3 = f2bf(v.w);
        shi[row][k4] = h0; shi[row][k4 + 1] = h1; shi[row][k4 + 2] = h2; shi[row][k4 + 3] = h3;
        smid[row][k4]     = f2bf(v.x - bf2f(h0));
        smid[row][k4 + 1] = f2bf(v.y - bf2f(h1));
        smid[row][k4 + 2] = f2bf(v.z - bf2f(h2));
        smid[row][k4 + 3] = f2bf(v.w - bf2f(h3));
    }
    __syncthreads();
    const int row = tid & 63;
#pragma unroll
    for (int i = 0; i < 16; ++i) {
        int c = i * 4 + (tid >> 6);
        size_t o = (size_t)c * nrows + r0 + row;
        ((ulonglong2*)dhi)[o]  = *(const ulonglong2*)&shi[row][c * 8];
        ((ulonglong2*)dmid)[o] = *(const ulonglong2*)&smid[row][c * 8];
    }
}

// ---------------- fused MFMA kernel: BM=32 x BN=256, BK=32, single-buffer, 2 blocks/CU ----------------
#define BM 32
#define BN 256
#define NCHUNK (NPROTO / BN)        // 16
#define NT 16                       // t-steps per chunk (BK=32 -> 4 cgroups per step)
#define CAP 80
#define PRUNE_AT 56
#define THRH 12.0f

__global__ __launch_bounds__(256, 2)
void attr_proto_mfma(const float* __restrict__ A, const float* __restrict__ Pr,
                     const float* __restrict__ U, float* __restrict__ out,
                     const unsigned short* __restrict__ wsAhi, const unsigned short* __restrict__ wsAmid,
                     const unsigned short* __restrict__ wsPhi, const unsigned short* __restrict__ wsPmid)
{
    __shared__ __align__(16) unsigned short sA[2][4][BM][8];    // [sp][g][row][8]    4 KB
    __shared__ __align__(16) unsigned short sP[2][4][BN][8];    // [sp][g][proto][8] 32 KB
    __shared__ float hZ[BM][CAP];                               // 10 KB
    __shared__ unsigned short hI[BM][CAP];                      // 5 KB
    __shared__ int cnt[BM];
    __shared__ float mRun[BM], lRun[BM];
    __shared__ float wMax[4][BM], wSum[4][BM];
    __shared__ float epZ[8][BM];
    __shared__ int epI[8][BM];
    __shared__ int pruneFlag;

    const int tid = threadIdx.x;
    const int w = tid >> 6;
    const int lane = tid & 63;
    const int l4 = lane & 15;
    const int lh = lane >> 4;
    const int row0 = blockIdx.x * BM;

    for (int r = tid; r < BM; r += 256) { cnt[r] = 0; mRun[r] = -1e30f; lRun[r] = 0.f; }
    if (tid == 0) pruneFlag = 0;

    // ---- 36 stage slots (9 per wave), running-pointer form -------------------
    const unsigned short* gp[9];
    int str9[9];        // per-t advance (shorts)
    int fx9[9];         // chunk-boundary fixup (shorts)
    unsigned short* ld9[9];
#pragma unroll
    for (int si = 0; si < 9; ++si) {
        int s = w * 9 + si;
        if (s < 4) {                       // A: sp=s>>1, gpair=s&1
            int sp = s >> 1, gpair = s & 1;
            int g = gpair * 2 + (lane >> 5);
            gp[si]  = (sp ? wsAmid : wsAhi) + ((size_t)g * NROWS + row0 + (lane & 31)) * 8;
            str9[si] = 4 * NROWS * 8;
            fx9[si]  = -16 * 4 * NROWS * 8;            // back to t=0 (A identical every chunk)
            ld9[si] = &sA[sp][gpair * 2][0][0] + (size_t)lane * 8;
        } else {                           // P: p=s-4: sp=p>>4, g=(p&15)>>2, q=p&3
            int p = s - 4;
            int sp = p >> 4, rem = p & 15, g = rem >> 2, q = rem & 3;
            gp[si]  = (sp ? wsPmid : wsPhi) + ((size_t)g * NPROTO + q * 64 + lane) * 8;
            str9[si] = 4 * NPROTO * 8;
            fx9[si]  = -16 * 4 * NPROTO * 8 + BN * 8;  // jump to next chunk's pbase, t=0
            ld9[si] = &sP[sp][g][q * 64][0] + (size_t)lane * 8;
        }
    }
#define DO_STAGE() { _Pragma("unroll") for (int si = 0; si < 9; ++si) { gl_lds16(gp[si], ld9[si]); gp[si] += str9[si]; } }

    DO_STAGE();          // prologue: stage (chunk0, t0); ptrs now at t1
    __syncthreads();     // drains vmcnt(0): tile 0 ready; also covers init stores

    for (int ch = 0; ch < NCHUNK; ++ch) {
        const int pbase = ch * BN;
        f32x4 acc[2][4];
#pragma unroll
        for (int mf = 0; mf < 2; ++mf)
#pragma unroll
            for (int nf = 0; nf < 4; ++nf) { acc[mf][nf][0]=0.f; acc[mf][nf][1]=0.f; acc[mf][nf][2]=0.f; acc[mf][nf][3]=0.f; }

#pragma unroll 2
        for (int t = 0; t < NT; ++t) {
            if (t > 0) {
                __syncthreads();      // all waves done reading previous tile
                DO_STAGE();           // stage tile t (in place)
                __syncthreads();      // drain: tile t ready
            }
            // compute (t-independent addressing: single buffer overwritten in place)
            short8 a[2][2], b[4][2];
#pragma unroll
            for (int mf = 0; mf < 2; ++mf) {
                a[mf][0] = *(const short8*)&sA[0][lh][mf * 16 + l4][0];
                a[mf][1] = *(const short8*)&sA[1][lh][mf * 16 + l4][0];
            }
#pragma unroll
            for (int nf = 0; nf < 4; ++nf) {
                b[nf][0] = *(const short8*)&sP[0][lh][w * 64 + nf * 16 + l4][0];
                b[nf][1] = *(const short8*)&sP[1][lh][w * 64 + nf * 16 + l4][0];
            }
#pragma unroll
            for (int mf = 0; mf < 2; ++mf)
#pragma unroll
                for (int nf = 0; nf < 4; ++nf) {
                    acc[mf][nf] = __builtin_amdgcn_mfma_f32_16x16x32_bf16(a[mf][0], b[nf][0], acc[mf][nf], 0, 0, 0);
                    acc[mf][nf] = __builtin_amdgcn_mfma_f32_16x16x32_bf16(a[mf][0], b[nf][1], acc[mf][nf], 0, 0, 0);
                    acc[mf][nf] = __builtin_amdgcn_mfma_f32_16x16x32_bf16(a[mf][1], b[nf][0], acc[mf][nf], 0, 0, 0);
                }
        }
        __syncthreads();              // all waves done reading tile 15
        if (ch + 1 < NCHUNK) {        // stage next chunk's tile 0 now; latency hides under softmax
#pragma unroll
            for (int si = 0; si < 9; ++si) gp[si] += fx9[si];
            DO_STAGE();
        }

        // ---- gumbel: acc -> z in place.  D layout: row=(lane>>4)*4+reg, col=lane&15
#pragma unroll
        for (int mf = 0; mf < 2; ++mf) {
            float uu[16];
            const int rb = row0 + mf * 16 + lh * 4;
#pragma unroll
            for (int nf = 0; nf < 4; ++nf)
#pragma unroll
                for (int r = 0; r < 4; ++r)
                    uu[nf * 4 + r] = U[(size_t)(rb + r) * NPROTO + pbase + w * 64 + nf * 16 + l4];
#pragma unroll
            for (int nf = 0; nf < 4; ++nf)
#pragma unroll
                for (int r = 0; r < 4; ++r) {
                    float g = -__logf(-__logf(uu[nf * 4 + r] + 1e-10f) + 1e-10f);
                    acc[mf][nf][r] = (acc[mf][nf][r] + g) * TINV;
                }
        }
        // wave-slice row max
#pragma unroll
        for (int mf = 0; mf < 2; ++mf) {
            f32x4 rm;
#pragma unroll
            for (int r = 0; r < 4; ++r)
                rm[r] = fmaxf(fmaxf(acc[mf][0][r], acc[mf][1][r]), fmaxf(acc[mf][2][r], acc[mf][3][r]));
#pragma unroll
            for (int off = 1; off < 16; off <<= 1)
#pragma unroll
                for (int r = 0; r < 4; ++r) rm[r] = fmaxf(rm[r], __shfl_xor(rm[r], off));
            if (l4 == 0)
#pragma unroll
                for (int r = 0; r < 4; ++r) wMax[w][mf * 16 + lh * 4 + r] = rm[r];
        }
        __syncthreads();
        // sums + heavy-list inserts
#pragma unroll
        for (int mf = 0; mf < 2; ++mf) {
#pragma unroll
            for (int r = 0; r < 4; ++r) {
                const int rl = mf * 16 + lh * 4 + r;
                float gm = fmaxf(fmaxf(wMax[0][rl], wMax[1][rl]), fmaxf(wMax[2][rl], wMax[3][rl]));
                float mn = fmaxf(mRun[rl], gm);
                float s = 0.f;
#pragma unroll
                for (int nf = 0; nf < 4; ++nf) s += __expf(acc[mf][nf][r] - mn);
#pragma unroll
                for (int off = 1; off < 16; off <<= 1) s += __shfl_xor(s, off);
                if (l4 == 0) wSum[w][rl] = s;
                float thrv = mn - THRH;
#pragma unroll
                for (int nf = 0; nf < 4; ++nf) {
                    float z = acc[mf][nf][r];
                    if (z > thrv) {
                        int pos = atomicAdd(&cnt[rl], 1);
                        if (pos < CAP) { hZ[rl][pos] = z; hI[rl][pos] = (unsigned short)(pbase + w * 64 + nf * 16 + l4); }
                    }
                }
            }
        }
        __syncthreads();
        if (tid < BM) {
            float gm = fmaxf(fmaxf(wMax[0][tid], wMax[1][tid]), fmaxf(wMax[2][tid], wMax[3][tid]));
            float mn = fmaxf(mRun[tid], gm);
            float S = wSum[0][tid] + wSum[1][tid] + wSum[2][tid] + wSum[3][tid];
            lRun[tid] = lRun[tid] * __expf(mRun[tid] - mn) + S;
            mRun[tid] = mn;
            if (cnt[tid] > PRUNE_AT) atomicOr(&pruneFlag, 1);
        }
        __syncthreads();
        if (pruneFlag) {
            for (int r = 0; r < BM; ++r) {
                int c0 = min(cnt[r], CAP);
                if (c0 > PRUNE_AT) {
                    float thr2 = mRun[r] - THRH;
                    float ez = 0.f; int ei = 0; bool keep = false;
                    if (tid < c0) { ez = hZ[r][tid]; ei = hI[r][tid]; keep = ez > thr2; }
                    __syncthreads();
                    if (tid == 0) cnt[r] = 0;
                    __syncthreads();
                    if (keep) { int pos = atomicAdd(&cnt[r], 1); hZ[r][pos] = ez; hI[r][pos] = (unsigned short)ei; }
                    __syncthreads();
                }
            }
            if (tid == 0) pruneFlag = 0;
        }
        __syncthreads();
    }

    // ---------------- epilogue phase 1: argmax via r1-replica fp32 serial recompute ----------------
    // np reference computes dist in fp32; serial fp32 FMA z matches it on this dataset (r1/r4/r5/r6/r7 PASS).
    __syncthreads();
    const int rq = tid & 31;     // row within block
    const int qq = tid >> 5;     // 8 groups per row
    {
        const int c = min(cnt[rq], CAP);
        float qm = -1e30f;
        for (int e = qq; e < c; e += 8) qm = fmaxf(qm, hZ[rq][e]);
        epZ[qq][rq] = qm;
    }
    __syncthreads();
    {
        const int c = min(cnt[rq], CAP);
        float bzr = epZ[0][rq];
#pragma unroll
        for (int q = 1; q < 8; ++q) bzr = fmaxf(bzr, epZ[q][rq]);
        const float win = bzr - 3.0f;
        float bestz = -1e30f; int bestp = 1 << 30;
        const float* ap = &A[(size_t)(row0 + rq) * DIM];
        for (int e = qq; e < c; e += 8) {
            if (hZ[rq][e] > win) {
                const int p = hI[rq][e];
                const float* pp = &Pr[(size_t)p * DIM];
                float d = 0.f;
                for (int k = 0; k < DIM; k += 4) {       // serial k order == r1's accumulation
                    float4 av = *(const float4*)&ap[k];
                    float4 pv = *(const float4*)&pp[k];
                    d = fmaf(av.x, pv.x, d);
                    d = fmaf(av.y, pv.y, d);
                    d = fmaf(av.z, pv.z, d);
                    d = fmaf(av.w, pv.w, d);
                }
                float u = U[(size_t)(row0 + rq) * NPROTO + p];
                float g = -logf(-logf(u + 1e-10f) + 1e-10f);  // accurate logf, as r1
                float zz = (d + g) * (1.0f / 0.9f);
                if (zz > bestz || (zz == bestz && p < bestp)) { bestz = zz; bestp = p; }
            }
        }
        __syncthreads();
        epZ[qq][rq] = bestz;
        epI[qq][rq] = bestp;
    }
    __syncthreads();
    if (tid < BM) {
        float bz2 = epZ[0][tid]; int bp2 = epI[0][tid];
#pragma unroll
        for (int q = 1; q < 8; ++q) {
            float z = epZ[q][tid]; int p = epI[q][tid];
            if (z > bz2 || (z == bz2 && p < bp2)) { bz2 = z; bp2 = p; }
        }
        out[IDX_OFF + row0 + tid] = (float)bp2;
    }

    // ---------------- epilogue phase 2: sparse PV gather, output write, loss ----------------
    float lossAcc = 0.f;
    for (int r = w; r < BM; r += 4) {
        const int grow = row0 + r;
        const int c = min(cnt[r], CAP);
        const float mm = mRun[r];
        const float li = 1.0f / lRun[r];
        float o[8];
#pragma unroll
        for (int q = 0; q < 8; ++q) o[q] = 0.f;
        for (int e = 0; e < c; ++e) {
            float wgt = __expf(hZ[r][e] - mm) * li;
            const float* pp = &Pr[(size_t)hI[r][e] * DIM + lane * 8];
            float4 p0 = *(const float4*)pp;
            float4 p1 = *(const float4*)(pp + 4);
            o[0] += wgt * p0.x; o[1] += wgt * p0.y; o[2] += wgt * p0.z; o[3] += wgt * p0.w;
            o[4] += wgt * p1.x; o[5] += wgt * p1.y; o[6] += wgt * p1.z; o[7] += wgt * p1.w;
        }
        const float* fr = &A[(size_t)grow * DIM + lane * 8];
        float4 f0 = *(const float4*)fr; float4 f1 = *(const float4*)(fr + 4);
        *(float4*)&out[(size_t)grow * DIM + lane * 8]     = make_float4(o[0], o[1], o[2], o[3]);
        *(float4*)&out[(size_t)grow * DIM + lane * 8 + 4] = make_float4(o[4], o[5], o[6], o[7]);
        lossAcc += fabsf(o[0] - f0.x) + fabsf(o[1] - f0.y) + fabsf(o[2] - f0.z) + fabsf(o[3] - f0.w)
                 + fabsf(o[4] - f1.x) + fabsf(o[5] - f1.y) + fabsf(o[6] - f1.z) + fabsf(o[7] - f1.w);
    }
#pragma unroll
    for (int off = 1; off < 64; off <<= 1) lossAcc += __shfl_xor(lossAcc, off);
    if (lane == 0) atomicAdd(&out[LOSS_OFF], lossAcc * (1.0f / ((float)NROWS * (float)DIM)));
}

// ---------------- fallback: r1 fp32 VALU kernel (used if ws too small) ----------------
#define FCAP 192
#define FTHR 20.0f

__global__ __launch_bounds__(256, 1)
void attr_proto_fused_valu(const float* __restrict__ A, const float* __restrict__ Pr,
                           const float* __restrict__ U, float* __restrict__ out)
{
    __shared__ __align__(16) float As[64][64 + 4];
    __shared__ __align__(16) float Bs[128][64 + 4];
    __shared__ float hZ[64][FCAP];
    __shared__ unsigned short hI[64][FCAP];
    __shared__ int cnt[64];
    __shared__ float mArr[64];
    __shared__ float lArr[64];
    __shared__ int pruneFlag;

    const int tid = threadIdx.x;
    const int tx = tid & 31;
    const int ty = tid >> 5;
    const int row0 = blockIdx.x * 64;

    for (int r = tid; r < 64; r += 256) cnt[r] = 0;
    if (tid == 0) pruneFlag = 0;

    float m[8], l[8], bz[8];
    int bi[8];
#pragma unroll
    for (int i = 0; i < 8; ++i) { m[i] = -INFINITY; l[i] = 0.0f; bz[i] = -INFINITY; bi[i] = 0; }
    __syncthreads();

    for (int ch = 0; ch < 32; ++ch) {
        const int pbase = ch * 128;
        float acc[8][4];
#pragma unroll
        for (int i = 0; i < 8; ++i)
#pragma unroll
            for (int j = 0; j < 4; ++j) acc[i][j] = 0.0f;

        for (int kk = 0; kk < DIM; kk += 64) {
#pragma unroll
            for (int q = 0; q < 4; ++q) {
                int lin = tid + q * 256;
                int lr = lin >> 4; int kq = (lin & 15) << 2;
                *(float4*)&As[lr][kq] = *(const float4*)&A[(size_t)(row0 + lr) * DIM + kk + kq];
            }
#pragma unroll
            for (int q = 0; q < 8; ++q) {
                int lin = tid + q * 256;
                int pr = lin >> 4; int kq = (lin & 15) << 2;
                *(float4*)&Bs[pr][kq] = *(const float4*)&Pr[(size_t)(pbase + pr) * DIM + kk + kq];
            }
            __syncthreads();
#pragma unroll 4
            for (int k4 = 0; k4 < 64; k4 += 4) {
                float4 av[8], bv[4];
#pragma unroll
                for (int i = 0; i < 8; ++i) av[i] = *(const float4*)&As[ty * 8 + i][k4];
#pragma unroll
                for (int j = 0; j < 4; ++j) bv[j] = *(const float4*)&Bs[tx + 32 * j][k4];
#pragma unroll
                for (int i = 0; i < 8; ++i)
#pragma unroll
                    for (int j = 0; j < 4; ++j) {
                        acc[i][j] += av[i].x * bv[j].x; acc[i][j] += av[i].y * bv[j].y;
                        acc[i][j] += av[i].z * bv[j].z; acc[i][j] += av[i].w * bv[j].w;
                    }
            }
            __syncthreads();
        }
#pragma unroll
        for (int i = 0; i < 8; ++i) {
            const int ri = ty * 8 + i;
            const size_t urow = (size_t)(row0 + ri) * NPROTO + pbase;
            float z[4]; float lmax = -INFINITY;
#pragma unroll
            for (int j = 0; j < 4; ++j) {
                float u = U[urow + tx + 32 * j];
                float g = -logf(-logf(u + 1e-10f) + 1e-10f);
                z[j] = (acc[i][j] + g) * TINV;
                lmax = fmaxf(lmax, z[j]);
            }
#pragma unroll
            for (int off = 16; off; off >>= 1) lmax = fmaxf(lmax, __shfl_xor(lmax, off, 32));
            const float mn = fmaxf(m[i], lmax);
            float s = 0.0f;
#pragma unroll
            for (int j = 0; j < 4; ++j) s += expf(z[j] - mn);
#pragma unroll
            for (int off = 16; off; off >>= 1) s += __shfl_xor(s, off, 32);
            l[i] = l[i] * expf(m[i] - mn) + s;
            m[i] = mn;
#pragma unroll
            for (int j = 0; j < 4; ++j) {
                const int p = pbase + tx + 32 * j;
                if (z[j] > bz[i]) { bz[i] = z[j]; bi[i] = p; }
                if (z[j] > mn - FTHR) {
                    int pos = atomicAdd(&cnt[ri], 1);
                    if (pos < FCAP) { hZ[ri][pos] = z[j]; hI[ri][pos] = (unsigned short)p; }
                }
            }
            if (tx == 0) {
                mArr[ri] = mn;
                if (cnt[ri] > 64) atomicOr(&pruneFlag, 1);
            }
        }
        __syncthreads();
        if (pruneFlag) {
            for (int r = 0; r < 64; ++r) {
                const int c0 = min(cnt[r], FCAP);
                if (c0 > 64) {
                    const float thr = mArr[r] - FTHR;
                    float ez = 0.0f; int ei = 0; bool keep = false;
                    if (tid < c0) { ez = hZ[r][tid]; ei = hI[r][tid]; keep = (ez > thr); }
                    __syncthreads();
                    if (tid == 0) cnt[r] = 0;
                    __syncthreads();
                    if (keep) { int pos = atomicAdd(&cnt[r], 1); hZ[r][pos] = ez; hI[r][pos] = (unsigned short)ei; }
                    __syncthreads();
                }
            }
            if (tid == 0) pruneFlag = 0;
            __syncthreads();
        }
    }
#pragma unroll
    for (int i = 0; i < 8; ++i) {
        const int ri = ty * 8 + i;
        float vz = bz[i]; int vi = bi[i];
#pragma unroll
        for (int off = 16; off; off >>= 1) {
            float oz = __shfl_xor(vz, off, 32); int oi = __shfl_xor(vi, off, 32);
            if (oz > vz || (oz == vz && oi < vi)) { vz = oz; vi = oi; }
        }
        if (tx == 0) { lArr[ri] = l[i]; out[IDX_OFF + row0 + ri] = (float)vi; }
    }
    __syncthreads();

    const int wv = tid >> 6;
    const int lane = tid & 63;
    float lossAcc = 0.0f;
    for (int r = wv; r < 64; r += 4) {
        const int grow = row0 + r;
        const int c = min(cnt[r], FCAP);
        const float mm = mArr[r];
        const float li = 1.0f / lArr[r];
        float o[8];
#pragma unroll
        for (int q = 0; q < 8; ++q) o[q] = 0.0f;
        for (int e = 0; e < c; ++e) {
            const float wg = expf(hZ[r][e] - mm) * li;
            const float* pp = &Pr[(size_t)hI[r][e] * DIM + lane * 8];
            float4 p0 = *(const float4*)pp; float4 p1 = *(const float4*)(pp + 4);
            o[0] += wg * p0.x; o[1] += wg * p0.y; o[2] += wg * p0.z; o[3] += wg * p0.w;
            o[4] += wg * p1.x; o[5] += wg * p1.y; o[6] += wg * p1.z; o[7] += wg * p1.w;
        }
        const float* fr = &A[(size_t)grow * DIM + lane * 8];
        float4 f0 = *(const float4*)fr; float4 f1 = *(const float4*)(fr + 4);
        *(float4*)&out[(size_t)grow * DIM + lane * 8]     = make_float4(o[0], o[1], o[2], o[3]);
        *(float4*)&out[(size_t)grow * DIM + lane * 8 + 4] = make_float4(o[4], o[5], o[6], o[7]);
        lossAcc += fabsf(o[0]-f0.x) + fabsf(o[1]-f0.y) + fabsf(o[2]-f0.z) + fabsf(o[3]-f0.w)
                 + fabsf(o[4]-f1.x) + fabsf(o[5]-f1.y) + fabsf(o[6]-f1.z) + fabsf(o[7]-f1.w);
    }
#pragma unroll
    for (int off = 32; off; off >>= 1) lossAcc += __shfl_xor(lossAcc, off, 64);
    if (lane == 0) atomicAdd(&out[LOSS_OFF], lossAcc * (1.0f / ((float)NROWS * (float)DIM)));
}

extern "C" void kernel_launch(void* const* d_in, const int* in_sizes, int n_in,
                              void* d_out, int out_size, void* d_ws, size_t ws_size,
                              hipStream_t stream)
{
    const float* A  = (const float*)d_in[0];
    const float* Pr = (const float*)d_in[1];
    const float* U  = (const float*)d_in[2];
    float* out = (float*)d_out;

    const size_t NA = (size_t)NROWS * DIM;     // 8388608 shorts per A split
    const size_t NP = (size_t)NPROTO * DIM;    // 2097152 shorts per P split
    const size_t need = (2 * NA + 2 * NP) * sizeof(unsigned short);   // 41,943,040 B

    if (ws_size >= need) {
        unsigned short* wsAhi  = (unsigned short*)d_ws;
        unsigned short* wsAmid = wsAhi + NA;
        unsigned short* wsPhi  = wsAmid + NA;
        unsigned short* wsPmid = wsPhi + NP;
        split_bf16_kernel<<<NROWS / 64, 256, 0, stream>>>(A, wsAhi, wsAmid, NROWS);
        split_bf16_kernel<<<NPROTO / 64, 256, 0, stream>>>(Pr, wsPhi, wsPmid, NPROTO);
        zero_loss_kernel<<<1, 1, 0, stream>>>(out);
        attr_proto_mfma<<<NROWS / BM, 256, 0, stream>>>(A, Pr, U, out, wsAhi, wsAmid, wsPhi, wsPmid);
    } else {
        zero_loss_kernel<<<1, 1, 0, stream>>>(out);
        attr_proto_fused_valu<<<NROWS / 64, 256, 0, stream>>>(A, Pr, U, out);
    }
}